// Round 11
// baseline (550.642 us; speedup 1.0000x reference)
//
#include <hip/hip_runtime.h>
#include <cstdint>
#include <cstddef>

// Problem constants
#define B_ 8
#define S_ 4096
#define H_ 1024
#define NH_ 16
#define DH_ 64
#define MTOK 32768  // B_*S_

typedef unsigned short u16;
typedef __bf16 bf16x8 __attribute__((ext_vector_type(8)));
typedef u16 u16x8 __attribute__((ext_vector_type(8)));
typedef u16 u16x4 __attribute__((ext_vector_type(4)));
typedef float f32x4 __attribute__((ext_vector_type(4)));

#define DEVFN static __device__ __forceinline__

DEVFN float bf2f(u16 u) {
  union { uint32_t u; float f; } c; c.u = ((uint32_t)u) << 16; return c.f;
}
DEVFN u16 f2bf(float f) {
  union { float f; uint32_t u; } c; c.f = f;
  uint32_t r = c.u + 0x7fffu + ((c.u >> 16) & 1u);  // RNE
  return (u16)(r >> 16);
}
DEVFN void gload16(const void* g, void* lds_p) {
  __builtin_amdgcn_global_load_lds(
      (const __attribute__((address_space(1))) void*)g,
      (__attribute__((address_space(3))) void*)lds_p, 16, 0, 0);
}

// ---------------------------------------------------------------------------
// Convert fp32 X -> bf16 Xb
__global__ __launch_bounds__(256) void k_cvt_x(const float* __restrict__ x,
                                               u16* __restrict__ xb) {
  const size_t i = ((size_t)blockIdx.x * 256 + threadIdx.x) * 8;
  f32x4 a = *(const f32x4*)(x + i);
  f32x4 b = *(const f32x4*)(x + i + 4);
  u16x8 o;
#pragma unroll
  for (int j = 0; j < 4; ++j) { o[j] = f2bf(a[j]); o[4 + j] = f2bf(b[j]); }
  *(u16x8*)(xb + i) = o;
}

// ---------------------------------------------------------------------------
// Weight transposes (bf16 B^T layouts):
// g<3:  Wt[g*1024+n][k] = W_g[k][n]
// g==3: Wdt[n][e]       = Wd[e][n]
__global__ __launch_bounds__(256) void k_wt(const float* __restrict__ Wq,
                                            const float* __restrict__ Wk,
                                            const float* __restrict__ Wv,
                                            const float* __restrict__ Wd,
                                            u16* __restrict__ Wt,
                                            u16* __restrict__ Wdt) {
  const int n = blockIdx.x * 256 + threadIdx.x;  // 0..1023
  const int kc = blockIdx.y;                     // k-chunk of 8
  const int g = blockIdx.z;                      // 0..3
  const float* W = (g == 0) ? Wq : (g == 1) ? Wk : (g == 2) ? Wv : Wd;
  u16x8 o;
#pragma unroll
  for (int j = 0; j < 8; ++j) o[j] = f2bf(W[(size_t)(kc * 8 + j) * 1024 + n]);
  u16* dst = (g < 3) ? (Wt + ((size_t)(g * 1024 + n)) * 1024 + kc * 8)
                     : (Wdt + (size_t)n * 1024 + kc * 8);
  *(u16x8*)dst = o;
}

// ---------------------------------------------------------------------------
// R1-family GEMM, BK=64 (halved barrier-drain events vs R1's BK=32):
// 128x128 tile, 4 waves (2Mx2N), 32KB single-buffer LDS, plain __syncthreads
// per K-tile, kh-split inner loop (live reg set identical to BK=32), direct
// scalar stores. LDS layout: [kh][128 rows][32 u16].
// EPI=0: QKV epilogue (bias + elu for Q,K; col segment of N=3072)
// EPI=1: plain bf16 store (ctx GEMM, Bt indexed per-batch: Bt + b*1M)
template <int EPI>
__global__ __launch_bounds__(256, 2) void k_g(
    const u16* __restrict__ A, const u16* __restrict__ Bt,
    u16* __restrict__ o0, u16* __restrict__ o1, u16* __restrict__ o2,
    const float* __restrict__ b0, const float* __restrict__ b1,
    const float* __restrict__ b2) {
  __shared__ u16 As[2 * 128 * 32];  // 16KB
  __shared__ u16 Bs[2 * 128 * 32];  // 16KB
  const int tid = threadIdx.x;
  const int w = tid >> 6, l = tid & 63;
  const int wm = w >> 1, wn = w & 1;
  const long row0 = (long)blockIdx.x * 128;
  const long col0 = (long)blockIdx.y * 128;
  const u16* Bt2 = Bt + (EPI == 1 ? ((size_t)(row0 >> 12) << 20) : (size_t)0);

  f32x4 acc[4][4];
#pragma unroll
  for (int i = 0; i < 4; ++i)
#pragma unroll
    for (int j = 0; j < 4; ++j) acc[i][j] = (f32x4){0.f, 0.f, 0.f, 0.f};

  // staging: 1024 chunks of 16B per matrix per tile; chunk c = i*256+tid ->
  // kh = i>>1, row = (i&1)*64 + (tid>>2), k-slot = (tid&3)*8 (+kh*32)
  const u16* gA = A + (row0 + (tid >> 2)) * 1024 + (tid & 3) * 8;
  const u16* gB = Bt2 + (col0 + (tid >> 2)) * 1024 + (tid & 3) * 8;
  u16* lA = As + w * 512;  // wave-uniform; +i*2048 u16 per chunk group
  u16* lB = Bs + w * 512;

  const int aoff = (wm * 64 + (l & 15)) * 32 + (l >> 4) * 8;
  const int boff = (wn * 64 + (l & 15)) * 32 + (l >> 4) * 8;

  for (int kt = 0; kt < 1024; kt += 64) {
#pragma unroll
    for (int i = 0; i < 4; ++i) {
      const int go = (i & 1) * 65536 + (i >> 1) * 32 + kt;
      gload16(gA + go, lA + i * 2048);
      gload16(gB + go, lB + i * 2048);
    }
    __syncthreads();  // drains vmcnt -> tiles visible
#pragma unroll
    for (int kh = 0; kh < 2; ++kh) {
      bf16x8 af[4], bfr[4];
#pragma unroll
      for (int mi = 0; mi < 4; ++mi)
        af[mi] = *(const bf16x8*)(As + kh * 4096 + aoff + mi * 512);
#pragma unroll
      for (int ni = 0; ni < 4; ++ni)
        bfr[ni] = *(const bf16x8*)(Bs + kh * 4096 + boff + ni * 512);
#pragma unroll
      for (int mi = 0; mi < 4; ++mi)
#pragma unroll
        for (int ni = 0; ni < 4; ++ni)
          acc[mi][ni] = __builtin_amdgcn_mfma_f32_16x16x32_bf16(
              af[mi], bfr[ni], acc[mi][ni], 0, 0, 0);
    }
    __syncthreads();  // all reads done before next stage overwrites
  }

  // Epilogue: D row = (l>>4)*4+reg, col = l&15 within each 16x16 frag
  const int rb = (int)row0 + wm * 64 + ((l >> 4) << 2);
  const int cb = (int)col0 + wn * 64 + (l & 15);
  if (EPI == 0) {
    const int seg = (int)(col0 >> 10);  // 0:Q 1:K 2:V (uniform per block)
    const int cl = cb & 1023;
    u16* outp = (seg == 0) ? o0 : (seg == 1) ? o1 : o2;
    const float* bias = (seg == 0) ? b0 : (seg == 1) ? b1 : b2;
#pragma unroll
    for (int mi = 0; mi < 4; ++mi)
#pragma unroll
      for (int ni = 0; ni < 4; ++ni) {
        const float bv_ = bias[cl + ni * 16];
#pragma unroll
        for (int r = 0; r < 4; ++r) {
          float v = acc[mi][ni][r] + bv_;
          if (seg < 2) v = v > 0.f ? v : expm1f(v);  // elu
          outp[(size_t)(rb + mi * 16 + r) * 1024 + cl + ni * 16] = f2bf(v);
        }
      }
  } else {
#pragma unroll
    for (int mi = 0; mi < 4; ++mi)
#pragma unroll
      for (int ni = 0; ni < 4; ++ni)
#pragma unroll
        for (int r = 0; r < 4; ++r)
          o0[(size_t)(rb + mi * 16 + r) * 1024 + cb + ni * 16] =
              f2bf(acc[mi][ni][r]);
  }
}

// ---------------------------------------------------------------------------
// Per-(token,head) L2 norm for Q only, in place (K norm fused into k_kv).
__global__ __launch_bounds__(256) void k_qn(u16* __restrict__ eq) {
  const int tid = threadIdx.x, w = tid >> 6, l = tid & 63;
  const long t = (long)blockIdx.x * 4 + w;
  const size_t base = (size_t)t * 1024 + (l >> 2) * 64 + (l & 3) * 16;
  u16x8 a = *(const u16x8*)(eq + base);
  u16x8 b = *(const u16x8*)(eq + base + 8);
  float f[16];
#pragma unroll
  for (int j = 0; j < 8; ++j) { f[j] = bf2f(a[j]); f[8 + j] = bf2f(b[j]); }
  float ss = 0.f;
#pragma unroll
  for (int j = 0; j < 16; ++j) ss += f[j] * f[j];
  ss += __shfl_xor(ss, 1);
  ss += __shfl_xor(ss, 2);
  const float rq = rsqrtf(ss);
  u16x8 oa, ob;
#pragma unroll
  for (int j = 0; j < 8; ++j) { oa[j] = f2bf(f[j] * rq); ob[j] = f2bf(f[8 + j] * rq); }
  *(u16x8*)(eq + base) = oa;
  *(u16x8*)(eq + base + 8) = ob;
}

// ---------------------------------------------------------------------------
// kv partials via MFMA with FUSED K-normalization:
// kvp[sc][b][h][d][e] = sum_{s in quarter} (ek[s,d]/||ek[s,:]||) * v[s,e]
__global__ __launch_bounds__(256) void k_kv(const u16* __restrict__ ek,
                                            const u16* __restrict__ vv,
                                            float* __restrict__ kvp) {
  __shared__ __align__(16) char lds[69632];  // 4 regions x 17408 B
  const int tid = threadIdx.x, w = tid >> 6, l = tid & 63;
  const int bid = blockIdx.x;  // sc + 4*(h + 16*b)
  const int sc = bid & 3, h = (bid >> 2) & 15, b = bid >> 6;
  const int tp = l >> 3, dgrp = l & 7;
  char* myk = lds + w * 17408;       // knT tile [64 d][64 s] u16 (128B rows)
  char* myv = myk + 8192;            // vT tile
  const long Tw = (long)b * 4096 + sc * 1024 + w * 256;
  const int d0 = dgrp * 8;

  f32x4 acc[4][4];
#pragma unroll
  for (int i = 0; i < 4; ++i)
#pragma unroll
    for (int j = 0; j < 4; ++j) acc[i][j] = (f32x4){0.f, 0.f, 0.f, 0.f};

  for (int st = 0; st < 4; ++st) {
    // ---- transpose-stage 64 tokens x 64 d for kn (normalized) and v
#pragma unroll
    for (int ro = 0; ro < 4; ++ro) {
      const int tl = ro * 16 + tp * 2;  // even local token
      const long T = Tw + st * 64 + tl;
      const u16* kp = ek + (size_t)T * 1024 + h * 64 + d0;
      const u16* vp = vv + (size_t)T * 1024 + h * 64 + d0;
      u16x8 k0 = *(const u16x8*)kp, k1 = *(const u16x8*)(kp + 1024);
      u16x8 v0 = *(const u16x8*)vp, v1 = *(const u16x8*)(vp + 1024);
      float f0[8], f1[8], s0 = 0.f, s1 = 0.f;
#pragma unroll
      for (int j = 0; j < 8; ++j) {
        f0[j] = bf2f(k0[j]); s0 += f0[j] * f0[j];
        f1[j] = bf2f(k1[j]); s1 += f1[j] * f1[j];
      }
      s0 += __shfl_xor(s0, 1); s0 += __shfl_xor(s0, 2); s0 += __shfl_xor(s0, 4);
      s1 += __shfl_xor(s1, 1); s1 += __shfl_xor(s1, 2); s1 += __shfl_xor(s1, 4);
      const float r0 = rsqrtf(s0), r1 = rsqrtf(s1);
#pragma unroll
      for (int j = 0; j < 8; ++j) {
        const int d = d0 + j;
        const int sw = (d & 8) ? 32 : 0;
        *(uint32_t*)(myk + d * 128 + ((tl * 2) ^ sw)) =
            (uint32_t)f2bf(f0[j] * r0) | ((uint32_t)f2bf(f1[j] * r1) << 16);
        *(uint32_t*)(myv + d * 128 + ((tl * 2) ^ sw)) =
            (uint32_t)v0[j] | ((uint32_t)v1[j] << 16);
      }
    }
    // ---- compute: D[d][e] += knT-tile . vT-tile  (K = 64 = 2 slices)
#pragma unroll
    for (int ksl = 0; ksl < 2; ++ksl) {
      const int sb = (ksl * 64 + (l >> 4) * 16) ^ ((l & 8) ? 32 : 0);
      bf16x8 a[4], bb[4];
#pragma unroll
      for (int mf = 0; mf < 4; ++mf)
        a[mf] = *(const bf16x8*)(myk + (mf * 16 + (l & 15)) * 128 + sb);
#pragma unroll
      for (int nf = 0; nf < 4; ++nf)
        bb[nf] = *(const bf16x8*)(myv + (nf * 16 + (l & 15)) * 128 + sb);
#pragma unroll
      for (int mf = 0; mf < 4; ++mf)
#pragma unroll
        for (int nf = 0; nf < 4; ++nf)
          acc[mf][nf] = __builtin_amdgcn_mfma_f32_16x16x32_bf16(
              a[mf], bb[nf], acc[mf][nf], 0, 0, 0);
    }
  }

  // ---- block reduction of 4 wave partials (rows padded to 68 f32)
  __syncthreads();
  float* lf = (float*)(lds + w * 17408);
#pragma unroll
  for (int mf = 0; mf < 4; ++mf)
#pragma unroll
    for (int nf = 0; nf < 4; ++nf)
#pragma unroll
      for (int r = 0; r < 4; ++r)
        lf[(mf * 16 + (l >> 4) * 4 + r) * 68 + nf * 16 + (l & 15)] =
            acc[mf][nf][r];
  __syncthreads();
  float* op = kvp + ((size_t)(sc * 8 + b) * 16 + h) * 4096;
  const float* l0 = (const float*)lds;
  const int dd = tid >> 2, eb = (tid & 3) * 16;
#pragma unroll
  for (int c = 0; c < 4; ++c) {
    f32x4 s = *(const f32x4*)(l0 + dd * 68 + eb + c * 4);
#pragma unroll
    for (int w2 = 1; w2 < 4; ++w2)
      s += *(const f32x4*)(l0 + w2 * 4352 + dd * 68 + eb + c * 4);
    *(f32x4*)(op + tid * 16 + c * 4) = s;
  }
}

// ---------------------------------------------------------------------------
// M2t[b][n][h*64+d] = (1/8) * sum_e kv[b,h][d][e] * Wdt[n][h*64+e] via MFMA,
// with FUSED kv partial-sum (reads the 4 kvp partials, sums in reg, stages
// bf16 tile to LDS -> no separate kvsum kernel / kvb buffer).
// Block = (ntile of 128, h, b); 4 waves, wave w owns 32 n-cols x 64 d-rows.
__global__ __launch_bounds__(256) void k_m2(const float* __restrict__ kvp,
                                            const u16* __restrict__ Wdt,
                                            u16* __restrict__ M2t) {
  __shared__ __align__(16) u16 lds[12288];  // kv: [64][64] @0; WdT: [128][64] @4096
  const int tid = threadIdx.x;
  const int w = tid >> 6, l = tid & 63;
  const int n0 = (int)blockIdx.x * 128, h = (int)blockIdx.y,
            b = (int)blockIdx.z;

  // stage WdT tile (16KB = 1024 x 16B): row n0+(c>>3), e-slot c&7 (+h*64)
#pragma unroll
  for (int g = 0; g < 4; ++g) {
    const int c = g * 256 + tid;
    gload16(Wdt + (size_t)(n0 + (c >> 3)) * 1024 + h * 64 + (c & 7) * 8,
            lds + 4096 + (g * 256 + w * 64) * 8);
  }
  // stage kv tile with fused 4-partial sum (reg-staged, linear ds_write)
  const size_t kvbase = ((size_t)(b * 16 + h)) * 4096;
#pragma unroll
  for (int g = 0; g < 2; ++g) {
    const int c = g * 256 + tid;  // chunk: row c>>3, e-slot c&7
    const float* p = kvp + kvbase + (size_t)(c >> 3) * 64 + (c & 7) * 8;
    f32x4 s0 = *(const f32x4*)p;
    f32x4 s1 = *(const f32x4*)(p + 4);
#pragma unroll
    for (int sc = 1; sc < 4; ++sc) {
      s0 += *(const f32x4*)(p + (size_t)sc * 524288);
      s1 += *(const f32x4*)(p + (size_t)sc * 524288 + 4);
    }
    u16x8 o;
#pragma unroll
    for (int j = 0; j < 4; ++j) { o[j] = f2bf(s0[j]); o[4 + j] = f2bf(s1[j]); }
    *(u16x8*)(lds + c * 8) = o;
  }
  __syncthreads();

  f32x4 acc[4][2];
#pragma unroll
  for (int i = 0; i < 4; ++i)
#pragma unroll
    for (int j = 0; j < 2; ++j) acc[i][j] = (f32x4){0.f, 0.f, 0.f, 0.f};

#pragma unroll
  for (int kh = 0; kh < 2; ++kh) {
    bf16x8 a[4], bb[2];
#pragma unroll
    for (int mf = 0; mf < 4; ++mf)
      a[mf] = *(const bf16x8*)(lds + (mf * 16 + (l & 15)) * 64 + kh * 32 +
                               (l >> 4) * 8);
#pragma unroll
    for (int nf = 0; nf < 2; ++nf)
      bb[nf] = *(const bf16x8*)(lds + 4096 +
                                (w * 32 + nf * 16 + (l & 15)) * 64 + kh * 32 +
                                (l >> 4) * 8);
#pragma unroll
    for (int mf = 0; mf < 4; ++mf)
#pragma unroll
      for (int nf = 0; nf < 2; ++nf)
        acc[mf][nf] = __builtin_amdgcn_mfma_f32_16x16x32_bf16(
            a[mf], bb[nf], acc[mf][nf], 0, 0, 0);
  }

  // store: D[d][n]; col n = w*32+nf*16+(l&15); rows d = mf*16+(l>>4)*4+r
  u16* outb = M2t + ((size_t)b << 20) + h * 64;
#pragma unroll
  for (int mf = 0; mf < 4; ++mf)
#pragma unroll
    for (int nf = 0; nf < 2; ++nf) {
      const int col = w * 32 + nf * 16 + (l & 15);
      u16x4 o;
#pragma unroll
      for (int r = 0; r < 4; ++r) o[r] = f2bf(acc[mf][nf][r] * 0.125f);
      *(u16x4*)(outb + (size_t)(n0 + col) * 1024 + mf * 16 + (l >> 4) * 4) = o;
    }
}

// ---------------------------------------------------------------------------
// LayerNorm(hid + bd + xb) * gamma + beta  -> fp32 out
__global__ __launch_bounds__(256) void k_ln(const u16* __restrict__ hid,
                                            const u16* __restrict__ xb,
                                            const float* __restrict__ bd,
                                            const float* __restrict__ g,
                                            const float* __restrict__ be,
                                            float* __restrict__ out) {
  const int tid = threadIdx.x, w = tid >> 6, l = tid & 63;
  const size_t base = (size_t)blockIdx.x * 1024 + tid * 4;
  u16x4 h4 = *(const u16x4*)(hid + base);
  u16x4 x4 = *(const u16x4*)(xb + base);
  f32x4 bd4 = *(const f32x4*)(bd + tid * 4);
  float v[4];
#pragma unroll
  for (int j = 0; j < 4; ++j) v[j] = bf2f(h4[j]) + bf2f(x4[j]) + bd4[j];
  float s = v[0] + v[1] + v[2] + v[3];
  float ss = v[0] * v[0] + v[1] * v[1] + v[2] * v[2] + v[3] * v[3];
#pragma unroll
  for (int o = 32; o > 0; o >>= 1) {
    s += __shfl_xor(s, o);
    ss += __shfl_xor(ss, o);
  }
  __shared__ float red[8];
  if (l == 0) { red[w] = s; red[w + 4] = ss; }
  __syncthreads();
  s = red[0] + red[1] + red[2] + red[3];
  ss = red[4] + red[5] + red[6] + red[7];
  const float mu = s * (1.0f / 1024.0f);
  const float var = ss * (1.0f / 1024.0f) - mu * mu;
  const float rstd = rsqrtf(var + 1e-12f);
  f32x4 g4 = *(const f32x4*)(g + tid * 4);
  f32x4 b4 = *(const f32x4*)(be + tid * 4);
  f32x4 o;
#pragma unroll
  for (int j = 0; j < 4; ++j) o[j] = (v[j] - mu) * rstd * g4[j] + b4[j];
  *(f32x4*)(out + base) = o;
}

// ---------------------------------------------------------------------------
extern "C" void kernel_launch(void* const* d_in, const int* in_sizes, int n_in,
                              void* d_out, int out_size, void* d_ws,
                              size_t ws_size, hipStream_t stream) {
  const float* X = (const float*)d_in[0];
  const float* Wq = (const float*)d_in[1];
  const float* bq = (const float*)d_in[2];
  const float* Wk = (const float*)d_in[3];
  const float* bk = (const float*)d_in[4];
  const float* Wv = (const float*)d_in[5];
  const float* bv = (const float*)d_in[6];
  const float* Wd = (const float*)d_in[7];
  const float* bd = (const float*)d_in[8];
  const float* gamma = (const float*)d_in[9];
  const float* beta = (const float*)d_in[10];
  float* out = (float*)d_out;

  char* ws = (char*)d_ws;
  u16* Xb = (u16*)(ws);                       // 64 MiB
  u16* Wt = (u16*)(ws + 67108864);            // 6 MiB  [3072][1024] bf16
  u16* eq = (u16*)(ws + 73400320);            // 64 MiB (-> qn in place)
  u16* ek = (u16*)(ws + 140509184);           // 64 MiB (raw eluK; later hid)
  u16* vb = (u16*)(ws + 207618048);           // 64 MiB
  u16* Wdt = (u16*)(ws + 274726912);          // 2 MiB  [1024][1024] bf16
  float* kvp = (float*)(ws + 276824064);      // 8 MiB (4 partials)
  u16* M2t = (u16*)(ws + 285212672);          // 16 MiB  [8][1024][1024] bf16
  // total ws use: 301,989,888 bytes

  k_cvt_x<<<16384, 256, 0, stream>>>(X, Xb);
  k_wt<<<dim3(4, 128, 4), 256, 0, stream>>>(Wq, Wk, Wv, Wd, Wt, Wdt);
  k_g<0><<<dim3(256, 24), 256, 0, stream>>>(Xb, Wt, eq, ek, vb, bq, bk, bv);
  k_qn<<<8192, 256, 0, stream>>>(eq);
  k_kv<<<512, 256, 0, stream>>>(ek, vb, kvp);
  k_m2<<<dim3(8, 16, 8), 256, 0, stream>>>(kvp, Wdt, M2t);
  k_g<1><<<dim3(256, 8), 256, 0, stream>>>(eq, M2t, ek, nullptr, nullptr,
                                           nullptr, nullptr, nullptr);
  k_ln<<<32768, 256, 0, stream>>>(ek, Xb, bd, gamma, beta, out);
}

// Round 12
// 519.347 us; speedup vs baseline: 1.0603x; 1.0603x over previous
//
#include <hip/hip_runtime.h>
#include <cstdint>
#include <cstddef>

// Problem constants
#define B_ 8
#define S_ 4096
#define H_ 1024
#define NH_ 16
#define DH_ 64
#define MTOK 32768  // B_*S_

typedef unsigned short u16;
typedef __bf16 bf16x8 __attribute__((ext_vector_type(8)));
typedef u16 u16x8 __attribute__((ext_vector_type(8)));
typedef u16 u16x4 __attribute__((ext_vector_type(4)));
typedef float f32x4 __attribute__((ext_vector_type(4)));

#define DEVFN static __device__ __forceinline__

DEVFN float bf2f(u16 u) {
  union { uint32_t u; float f; } c; c.u = ((uint32_t)u) << 16; return c.f;
}
DEVFN u16 f2bf(float f) {
  union { float f; uint32_t u; } c; c.f = f;
  uint32_t r = c.u + 0x7fffu + ((c.u >> 16) & 1u);  // RNE
  return (u16)(r >> 16);
}
DEVFN void gload16(const void* g, void* lds_p) {
  __builtin_amdgcn_global_load_lds(
      (const __attribute__((address_space(1))) void*)g,
      (__attribute__((address_space(3))) void*)lds_p, 16, 0, 0);
}

// ---------------------------------------------------------------------------
// Convert fp32 X -> bf16 Xb
__global__ __launch_bounds__(256) void k_cvt_x(const float* __restrict__ x,
                                               u16* __restrict__ xb) {
  const size_t i = ((size_t)blockIdx.x * 256 + threadIdx.x) * 8;
  f32x4 a = *(const f32x4*)(x + i);
  f32x4 b = *(const f32x4*)(x + i + 4);
  u16x8 o;
#pragma unroll
  for (int j = 0; j < 4; ++j) { o[j] = f2bf(a[j]); o[4 + j] = f2bf(b[j]); }
  *(u16x8*)(xb + i) = o;
}

// ---------------------------------------------------------------------------
// Weight transposes (bf16 B^T layouts):
// g<3:  Wt[g*1024+n][k] = W_g[k][n]
// g==3: Wdt[n][e]       = Wd[e][n]
__global__ __launch_bounds__(256) void k_wt(const float* __restrict__ Wq,
                                            const float* __restrict__ Wk,
                                            const float* __restrict__ Wv,
                                            const float* __restrict__ Wd,
                                            u16* __restrict__ Wt,
                                            u16* __restrict__ Wdt) {
  const int n = blockIdx.x * 256 + threadIdx.x;  // 0..1023
  const int kc = blockIdx.y;                     // k-chunk of 8
  const int g = blockIdx.z;                      // 0..3
  const float* W = (g == 0) ? Wq : (g == 1) ? Wk : (g == 2) ? Wv : Wd;
  u16x8 o;
#pragma unroll
  for (int j = 0; j < 8; ++j) o[j] = f2bf(W[(size_t)(kc * 8 + j) * 1024 + n]);
  u16* dst = (g < 3) ? (Wt + ((size_t)(g * 1024 + n)) * 1024 + kc * 8)
                     : (Wdt + (size_t)n * 1024 + kc * 8);
  *(u16x8*)dst = o;
}

// ---------------------------------------------------------------------------
// R1-family GEMM, BK=64, 128x128 tile, 4 waves (2Mx2N), 32KB single-buffer
// LDS, plain __syncthreads per K-tile, kh-split inner loop, direct stores.
// NEW (R12): XCD-chunked grid mapping with by-fastest order per XCD so the
// per-XCD resident working set is A ~1.5MB (L2-hit) + B panels -> the
// vmcnt(0) drain latency drops from HBM (~900cy) to L2/L3 class.
// EPI=0: QKV (bias + elu for Q,K), 1D grid 6144 = 8 xcd x (24 by x 32 bx).
// EPI=1: ctx (plain store, Bt per-batch), 1D grid 2048 = 8 x (8 by x 32 bx).
template <int EPI>
__global__ __launch_bounds__(256, 2) void k_g(
    const u16* __restrict__ A, const u16* __restrict__ Bt,
    u16* __restrict__ o0, u16* __restrict__ o1, u16* __restrict__ o2,
    const float* __restrict__ b0, const float* __restrict__ b1,
    const float* __restrict__ b2) {
  __shared__ u16 As[2 * 128 * 32];  // 16KB
  __shared__ u16 Bs[2 * 128 * 32];  // 16KB
  const int tid = threadIdx.x;
  const int w = tid >> 6, l = tid & 63;
  const int wm = w >> 1, wn = w & 1;

  // XCD-chunked decode: xcd = bid&7 owns 32 consecutive bx panels; by cycles
  // fastest so the A panel is reused across all by before moving on.
  const int bid = (int)blockIdx.x;
  const int xcd = bid & 7, c = bid >> 3;
  int bx, by;
  if (EPI == 0) { by = c % 24; bx = xcd * 32 + c / 24; }
  else          { by = c & 7;  bx = xcd * 32 + (c >> 3); }

  const long row0 = (long)bx * 128;
  const long col0 = (long)by * 128;
  const u16* Bt2 = Bt + (EPI == 1 ? ((size_t)(row0 >> 12) << 20) : (size_t)0);

  f32x4 acc[4][4];
#pragma unroll
  for (int i = 0; i < 4; ++i)
#pragma unroll
    for (int j = 0; j < 4; ++j) acc[i][j] = (f32x4){0.f, 0.f, 0.f, 0.f};

  // staging: 1024 chunks of 16B per matrix per tile; chunk c = i*256+tid ->
  // kh = i>>1, row = (i&1)*64 + (tid>>2), k-slot = (tid&3)*8 (+kh*32)
  const u16* gA = A + (row0 + (tid >> 2)) * 1024 + (tid & 3) * 8;
  const u16* gB = Bt2 + (col0 + (tid >> 2)) * 1024 + (tid & 3) * 8;
  u16* lA = As + w * 512;  // wave-uniform; +i*2048 u16 per chunk group
  u16* lB = Bs + w * 512;

  const int aoff = (wm * 64 + (l & 15)) * 32 + (l >> 4) * 8;
  const int boff = (wn * 64 + (l & 15)) * 32 + (l >> 4) * 8;

  for (int kt = 0; kt < 1024; kt += 64) {
#pragma unroll
    for (int i = 0; i < 4; ++i) {
      const int go = (i & 1) * 65536 + (i >> 1) * 32 + kt;
      gload16(gA + go, lA + i * 2048);
      gload16(gB + go, lB + i * 2048);
    }
    __syncthreads();  // drains vmcnt -> tiles visible
#pragma unroll
    for (int kh = 0; kh < 2; ++kh) {
      bf16x8 af[4], bfr[4];
#pragma unroll
      for (int mi = 0; mi < 4; ++mi)
        af[mi] = *(const bf16x8*)(As + kh * 4096 + aoff + mi * 512);
#pragma unroll
      for (int ni = 0; ni < 4; ++ni)
        bfr[ni] = *(const bf16x8*)(Bs + kh * 4096 + boff + ni * 512);
#pragma unroll
      for (int mi = 0; mi < 4; ++mi)
#pragma unroll
        for (int ni = 0; ni < 4; ++ni)
          acc[mi][ni] = __builtin_amdgcn_mfma_f32_16x16x32_bf16(
              af[mi], bfr[ni], acc[mi][ni], 0, 0, 0);
    }
    __syncthreads();  // all reads done before next stage overwrites
  }

  // Epilogue: D row = (l>>4)*4+reg, col = l&15 within each 16x16 frag
  const int rb = (int)row0 + wm * 64 + ((l >> 4) << 2);
  const int cb = (int)col0 + wn * 64 + (l & 15);
  if (EPI == 0) {
    const int seg = (int)(col0 >> 10);  // 0:Q 1:K 2:V (uniform per block)
    const int cl = cb & 1023;
    u16* outp = (seg == 0) ? o0 : (seg == 1) ? o1 : o2;
    const float* bias = (seg == 0) ? b0 : (seg == 1) ? b1 : b2;
#pragma unroll
    for (int mi = 0; mi < 4; ++mi)
#pragma unroll
      for (int ni = 0; ni < 4; ++ni) {
        const float bv_ = bias[cl + ni * 16];
#pragma unroll
        for (int r = 0; r < 4; ++r) {
          float v = acc[mi][ni][r] + bv_;
          if (seg < 2) v = v > 0.f ? v : expm1f(v);  // elu
          outp[(size_t)(rb + mi * 16 + r) * 1024 + cl + ni * 16] = f2bf(v);
        }
      }
  } else {
#pragma unroll
    for (int mi = 0; mi < 4; ++mi)
#pragma unroll
      for (int ni = 0; ni < 4; ++ni)
#pragma unroll
        for (int r = 0; r < 4; ++r)
          o0[(size_t)(rb + mi * 16 + r) * 1024 + cb + ni * 16] =
              f2bf(acc[mi][ni][r]);
  }
}

// ---------------------------------------------------------------------------
// Per-(token,head) L2 norm for Q only, in place (K norm fused into k_kv).
__global__ __launch_bounds__(256) void k_qn(u16* __restrict__ eq) {
  const int tid = threadIdx.x, w = tid >> 6, l = tid & 63;
  const long t = (long)blockIdx.x * 4 + w;
  const size_t base = (size_t)t * 1024 + (l >> 2) * 64 + (l & 3) * 16;
  u16x8 a = *(const u16x8*)(eq + base);
  u16x8 b = *(const u16x8*)(eq + base + 8);
  float f[16];
#pragma unroll
  for (int j = 0; j < 8; ++j) { f[j] = bf2f(a[j]); f[8 + j] = bf2f(b[j]); }
  float ss = 0.f;
#pragma unroll
  for (int j = 0; j < 16; ++j) ss += f[j] * f[j];
  ss += __shfl_xor(ss, 1);
  ss += __shfl_xor(ss, 2);
  const float rq = rsqrtf(ss);
  u16x8 oa, ob;
#pragma unroll
  for (int j = 0; j < 8; ++j) { oa[j] = f2bf(f[j] * rq); ob[j] = f2bf(f[8 + j] * rq); }
  *(u16x8*)(eq + base) = oa;
  *(u16x8*)(eq + base + 8) = ob;
}

// ---------------------------------------------------------------------------
// kv partials via MFMA with FUSED K-normalization:
// kvp[sc][b][h][d][e] = sum_{s in quarter} (ek[s,d]/||ek[s,:]||) * v[s,e]
__global__ __launch_bounds__(256) void k_kv(const u16* __restrict__ ek,
                                            const u16* __restrict__ vv,
                                            float* __restrict__ kvp) {
  __shared__ __align__(16) char lds[69632];  // 4 regions x 17408 B
  const int tid = threadIdx.x, w = tid >> 6, l = tid & 63;
  const int bid = blockIdx.x;  // sc + 4*(h + 16*b)
  const int sc = bid & 3, h = (bid >> 2) & 15, b = bid >> 6;
  const int tp = l >> 3, dgrp = l & 7;
  char* myk = lds + w * 17408;       // knT tile [64 d][64 s] u16 (128B rows)
  char* myv = myk + 8192;            // vT tile
  const long Tw = (long)b * 4096 + sc * 1024 + w * 256;
  const int d0 = dgrp * 8;

  f32x4 acc[4][4];
#pragma unroll
  for (int i = 0; i < 4; ++i)
#pragma unroll
    for (int j = 0; j < 4; ++j) acc[i][j] = (f32x4){0.f, 0.f, 0.f, 0.f};

  for (int st = 0; st < 4; ++st) {
    // ---- transpose-stage 64 tokens x 64 d for kn (normalized) and v
#pragma unroll
    for (int ro = 0; ro < 4; ++ro) {
      const int tl = ro * 16 + tp * 2;  // even local token
      const long T = Tw + st * 64 + tl;
      const u16* kp = ek + (size_t)T * 1024 + h * 64 + d0;
      const u16* vp = vv + (size_t)T * 1024 + h * 64 + d0;
      u16x8 k0 = *(const u16x8*)kp, k1 = *(const u16x8*)(kp + 1024);
      u16x8 v0 = *(const u16x8*)vp, v1 = *(const u16x8*)(vp + 1024);
      float f0[8], f1[8], s0 = 0.f, s1 = 0.f;
#pragma unroll
      for (int j = 0; j < 8; ++j) {
        f0[j] = bf2f(k0[j]); s0 += f0[j] * f0[j];
        f1[j] = bf2f(k1[j]); s1 += f1[j] * f1[j];
      }
      s0 += __shfl_xor(s0, 1); s0 += __shfl_xor(s0, 2); s0 += __shfl_xor(s0, 4);
      s1 += __shfl_xor(s1, 1); s1 += __shfl_xor(s1, 2); s1 += __shfl_xor(s1, 4);
      const float r0 = rsqrtf(s0), r1 = rsqrtf(s1);
#pragma unroll
      for (int j = 0; j < 8; ++j) {
        const int d = d0 + j;
        const int sw = (d & 8) ? 32 : 0;
        *(uint32_t*)(myk + d * 128 + ((tl * 2) ^ sw)) =
            (uint32_t)f2bf(f0[j] * r0) | ((uint32_t)f2bf(f1[j] * r1) << 16);
        *(uint32_t*)(myv + d * 128 + ((tl * 2) ^ sw)) =
            (uint32_t)v0[j] | ((uint32_t)v1[j] << 16);
      }
    }
    // ---- compute: D[d][e] += knT-tile . vT-tile  (K = 64 = 2 slices)
#pragma unroll
    for (int ksl = 0; ksl < 2; ++ksl) {
      const int sb = (ksl * 64 + (l >> 4) * 16) ^ ((l & 8) ? 32 : 0);
      bf16x8 a[4], bb[4];
#pragma unroll
      for (int mf = 0; mf < 4; ++mf)
        a[mf] = *(const bf16x8*)(myk + (mf * 16 + (l & 15)) * 128 + sb);
#pragma unroll
      for (int nf = 0; nf < 4; ++nf)
        bb[nf] = *(const bf16x8*)(myv + (nf * 16 + (l & 15)) * 128 + sb);
#pragma unroll
      for (int mf = 0; mf < 4; ++mf)
#pragma unroll
        for (int nf = 0; nf < 4; ++nf)
          acc[mf][nf] = __builtin_amdgcn_mfma_f32_16x16x32_bf16(
              a[mf], bb[nf], acc[mf][nf], 0, 0, 0);
    }
  }

  // ---- block reduction of 4 wave partials (rows padded to 68 f32)
  __syncthreads();
  float* lf = (float*)(lds + w * 17408);
#pragma unroll
  for (int mf = 0; mf < 4; ++mf)
#pragma unroll
    for (int nf = 0; nf < 4; ++nf)
#pragma unroll
      for (int r = 0; r < 4; ++r)
        lf[(mf * 16 + (l >> 4) * 4 + r) * 68 + nf * 16 + (l & 15)] =
            acc[mf][nf][r];
  __syncthreads();
  float* op = kvp + ((size_t)(sc * 8 + b) * 16 + h) * 4096;
  const float* l0 = (const float*)lds;
  const int dd = tid >> 2, eb = (tid & 3) * 16;
#pragma unroll
  for (int c = 0; c < 4; ++c) {
    f32x4 s = *(const f32x4*)(l0 + dd * 68 + eb + c * 4);
#pragma unroll
    for (int w2 = 1; w2 < 4; ++w2)
      s += *(const f32x4*)(l0 + w2 * 4352 + dd * 68 + eb + c * 4);
    *(f32x4*)(op + tid * 16 + c * 4) = s;
  }
}

// ---------------------------------------------------------------------------
// M2t[b][n][h*64+d] = (1/8) * sum_e kv[b,h][d][e] * Wdt[n][h*64+e] via MFMA,
// with FUSED kv partial-sum (reads the 4 kvp partials, sums in reg, stages
// bf16 tile to LDS).
__global__ __launch_bounds__(256) void k_m2(const float* __restrict__ kvp,
                                            const u16* __restrict__ Wdt,
                                            u16* __restrict__ M2t) {
  __shared__ __align__(16) u16 lds[12288];  // kv: [64][64] @0; WdT: [128][64] @4096
  const int tid = threadIdx.x;
  const int w = tid >> 6, l = tid & 63;
  const int n0 = (int)blockIdx.x * 128, h = (int)blockIdx.y,
            b = (int)blockIdx.z;

  // stage WdT tile (16KB = 1024 x 16B): row n0+(c>>3), e-slot c&7 (+h*64)
#pragma unroll
  for (int g = 0; g < 4; ++g) {
    const int c = g * 256 + tid;
    gload16(Wdt + (size_t)(n0 + (c >> 3)) * 1024 + h * 64 + (c & 7) * 8,
            lds + 4096 + (g * 256 + w * 64) * 8);
  }
  // stage kv tile with fused 4-partial sum (reg-staged, linear ds_write)
  const size_t kvbase = ((size_t)(b * 16 + h)) * 4096;
#pragma unroll
  for (int g = 0; g < 2; ++g) {
    const int c = g * 256 + tid;  // chunk: row c>>3, e-slot c&7
    const float* p = kvp + kvbase + (size_t)(c >> 3) * 64 + (c & 7) * 8;
    f32x4 s0 = *(const f32x4*)p;
    f32x4 s1 = *(const f32x4*)(p + 4);
#pragma unroll
    for (int sc = 1; sc < 4; ++sc) {
      s0 += *(const f32x4*)(p + (size_t)sc * 524288);
      s1 += *(const f32x4*)(p + (size_t)sc * 524288 + 4);
    }
    u16x8 o;
#pragma unroll
    for (int j = 0; j < 4; ++j) { o[j] = f2bf(s0[j]); o[4 + j] = f2bf(s1[j]); }
    *(u16x8*)(lds + c * 8) = o;
  }
  __syncthreads();

  f32x4 acc[4][2];
#pragma unroll
  for (int i = 0; i < 4; ++i)
#pragma unroll
    for (int j = 0; j < 2; ++j) acc[i][j] = (f32x4){0.f, 0.f, 0.f, 0.f};

#pragma unroll
  for (int kh = 0; kh < 2; ++kh) {
    bf16x8 a[4], bb[2];
#pragma unroll
    for (int mf = 0; mf < 4; ++mf)
      a[mf] = *(const bf16x8*)(lds + (mf * 16 + (l & 15)) * 64 + kh * 32 +
                               (l >> 4) * 8);
#pragma unroll
    for (int nf = 0; nf < 2; ++nf)
      bb[nf] = *(const bf16x8*)(lds + 4096 +
                                (w * 32 + nf * 16 + (l & 15)) * 64 + kh * 32 +
                                (l >> 4) * 8);
#pragma unroll
    for (int mf = 0; mf < 4; ++mf)
#pragma unroll
      for (int nf = 0; nf < 2; ++nf)
        acc[mf][nf] = __builtin_amdgcn_mfma_f32_16x16x32_bf16(
            a[mf], bb[nf], acc[mf][nf], 0, 0, 0);
  }

  // store: D[d][n]; col n = w*32+nf*16+(l&15); rows d = mf*16+(l>>4)*4+r
  u16* outb = M2t + ((size_t)b << 20) + h * 64;
#pragma unroll
  for (int mf = 0; mf < 4; ++mf)
#pragma unroll
    for (int nf = 0; nf < 2; ++nf) {
      const int col = w * 32 + nf * 16 + (l & 15);
      u16x4 o;
#pragma unroll
      for (int r = 0; r < 4; ++r) o[r] = f2bf(acc[mf][nf][r] * 0.125f);
      *(u16x4*)(outb + (size_t)(n0 + col) * 1024 + mf * 16 + (l >> 4) * 4) = o;
    }
}

// ---------------------------------------------------------------------------
// LayerNorm(hid + bd + xb) * gamma + beta  -> fp32 out
__global__ __launch_bounds__(256) void k_ln(const u16* __restrict__ hid,
                                            const u16* __restrict__ xb,
                                            const float* __restrict__ bd,
                                            const float* __restrict__ g,
                                            const float* __restrict__ be,
                                            float* __restrict__ out) {
  const int tid = threadIdx.x, w = tid >> 6, l = tid & 63;
  const size_t base = (size_t)blockIdx.x * 1024 + tid * 4;
  u16x4 h4 = *(const u16x4*)(hid + base);
  u16x4 x4 = *(const u16x4*)(xb + base);
  f32x4 bd4 = *(const f32x4*)(bd + tid * 4);
  float v[4];
#pragma unroll
  for (int j = 0; j < 4; ++j) v[j] = bf2f(h4[j]) + bf2f(x4[j]) + bd4[j];
  float s = v[0] + v[1] + v[2] + v[3];
  float ss = v[0] * v[0] + v[1] * v[1] + v[2] * v[2] + v[3] * v[3];
#pragma unroll
  for (int o = 32; o > 0; o >>= 1) {
    s += __shfl_xor(s, o);
    ss += __shfl_xor(ss, o);
  }
  __shared__ float red[8];
  if (l == 0) { red[w] = s; red[w + 4] = ss; }
  __syncthreads();
  s = red[0] + red[1] + red[2] + red[3];
  ss = red[4] + red[5] + red[6] + red[7];
  const float mu = s * (1.0f / 1024.0f);
  const float var = ss * (1.0f / 1024.0f) - mu * mu;
  const float rstd = rsqrtf(var + 1e-12f);
  f32x4 g4 = *(const f32x4*)(g + tid * 4);
  f32x4 b4 = *(const f32x4*)(be + tid * 4);
  f32x4 o;
#pragma unroll
  for (int j = 0; j < 4; ++j) o[j] = (v[j] - mu) * rstd * g4[j] + b4[j];
  *(f32x4*)(out + base) = o;
}

// ---------------------------------------------------------------------------
extern "C" void kernel_launch(void* const* d_in, const int* in_sizes, int n_in,
                              void* d_out, int out_size, void* d_ws,
                              size_t ws_size, hipStream_t stream) {
  const float* X = (const float*)d_in[0];
  const float* Wq = (const float*)d_in[1];
  const float* bq = (const float*)d_in[2];
  const float* Wk = (const float*)d_in[3];
  const float* bk = (const float*)d_in[4];
  const float* Wv = (const float*)d_in[5];
  const float* bv = (const float*)d_in[6];
  const float* Wd = (const float*)d_in[7];
  const float* bd = (const float*)d_in[8];
  const float* gamma = (const float*)d_in[9];
  const float* beta = (const float*)d_in[10];
  float* out = (float*)d_out;

  char* ws = (char*)d_ws;
  u16* Xb = (u16*)(ws);                       // 64 MiB
  u16* Wt = (u16*)(ws + 67108864);            // 6 MiB  [3072][1024] bf16
  u16* eq = (u16*)(ws + 73400320);            // 64 MiB (-> qn in place)
  u16* ek = (u16*)(ws + 140509184);           // 64 MiB (raw eluK; later hid)
  u16* vb = (u16*)(ws + 207618048);           // 64 MiB
  u16* Wdt = (u16*)(ws + 274726912);          // 2 MiB  [1024][1024] bf16
  float* kvp = (float*)(ws + 276824064);      // 8 MiB (4 partials)
  u16* M2t = (u16*)(ws + 285212672);          // 16 MiB  [8][1024][1024] bf16
  // total ws use: 301,989,888 bytes

  k_cvt_x<<<16384, 256, 0, stream>>>(X, Xb);
  k_wt<<<dim3(4, 128, 4), 256, 0, stream>>>(Wq, Wk, Wv, Wd, Wt, Wdt);
  k_g<0><<<6144, 256, 0, stream>>>(Xb, Wt, eq, ek, vb, bq, bk, bv);
  k_qn<<<8192, 256, 0, stream>>>(eq);
  k_kv<<<512, 256, 0, stream>>>(ek, vb, kvp);
  k_m2<<<dim3(8, 16, 8), 256, 0, stream>>>(kvp, Wdt, M2t);
  k_g<1><<<2048, 256, 0, stream>>>(eq, M2t, ek, nullptr, nullptr, nullptr,
                                   nullptr, nullptr);
  k_ln<<<32768, 256, 0, stream>>>(ek, Xb, bd, gamma, beta, out);
}

// Round 13
// 491.395 us; speedup vs baseline: 1.1206x; 1.0569x over previous
//
#include <hip/hip_runtime.h>
#include <cstdint>
#include <cstddef>

// Problem constants
#define B_ 8
#define S_ 4096
#define H_ 1024
#define NH_ 16
#define DH_ 64
#define MTOK 32768  // B_*S_

typedef unsigned short u16;
typedef __bf16 bf16x8 __attribute__((ext_vector_type(8)));
typedef u16 u16x8 __attribute__((ext_vector_type(8)));
typedef u16 u16x4 __attribute__((ext_vector_type(4)));
typedef float f32x4 __attribute__((ext_vector_type(4)));

#define DEVFN static __device__ __forceinline__

DEVFN float bf2f(u16 u) {
  union { uint32_t u; float f; } c; c.u = ((uint32_t)u) << 16; return c.f;
}
DEVFN u16 f2bf(float f) {
  union { float f; uint32_t u; } c; c.f = f;
  uint32_t r = c.u + 0x7fffu + ((c.u >> 16) & 1u);  // RNE
  return (u16)(r >> 16);
}
DEVFN void gload16(const void* g, void* lds_p) {
  __builtin_amdgcn_global_load_lds(
      (const __attribute__((address_space(1))) void*)g,
      (__attribute__((address_space(3))) void*)lds_p, 16, 0, 0);
}

// ---------------------------------------------------------------------------
// Convert fp32 X -> bf16 Xb
__global__ __launch_bounds__(256) void k_cvt_x(const float* __restrict__ x,
                                               u16* __restrict__ xb) {
  const size_t i = ((size_t)blockIdx.x * 256 + threadIdx.x) * 8;
  f32x4 a = *(const f32x4*)(x + i);
  f32x4 b = *(const f32x4*)(x + i + 4);
  u16x8 o;
#pragma unroll
  for (int j = 0; j < 4; ++j) { o[j] = f2bf(a[j]); o[4 + j] = f2bf(b[j]); }
  *(u16x8*)(xb + i) = o;
}

// ---------------------------------------------------------------------------
// Weight transposes (bf16 B^T layouts):
// g<3:  Wt[g*1024+n][k] = W_g[k][n]
// g==3: Wdt[n][e]       = Wd[e][n]
__global__ __launch_bounds__(256) void k_wt(const float* __restrict__ Wq,
                                            const float* __restrict__ Wk,
                                            const float* __restrict__ Wv,
                                            const float* __restrict__ Wd,
                                            u16* __restrict__ Wt,
                                            u16* __restrict__ Wdt) {
  const int n = blockIdx.x * 256 + threadIdx.x;  // 0..1023
  const int kc = blockIdx.y;                     // k-chunk of 8
  const int g = blockIdx.z;                      // 0..3
  const float* W = (g == 0) ? Wq : (g == 1) ? Wk : (g == 2) ? Wv : Wd;
  u16x8 o;
#pragma unroll
  for (int j = 0; j < 8; ++j) o[j] = f2bf(W[(size_t)(kc * 8 + j) * 1024 + n]);
  u16* dst = (g < 3) ? (Wt + ((size_t)(g * 1024 + n)) * 1024 + kc * 8)
                     : (Wdt + (size_t)n * 1024 + kc * 8);
  *(u16x8*)dst = o;
}

// ---------------------------------------------------------------------------
// R1-family GEMM, widened tile: 128x256, BK=64, 512 threads = 8 waves (2Mx4N),
// 48KB single-buffer LDS, plain __syncthreads per K-tile, kh-split inner loop,
// direct scalar stores. Per-wave geometry identical to the proven 128x128
// kernel (64x64 out, 32 MFMA/K-tile, 64 AGPR); block count halved -> half the
// vmcnt-drain events and half the B-panel fetches.
// XCD-chunked grid: xcd=bid&7 owns 32 consecutive bx; by cycles fastest.
// EPI=0: QKV (bias + elu for Q,K), grid 3072 = 8 x (12 by x 32 bx).
// EPI=1: ctx (plain store, Bt per-batch), grid 1024 = 8 x (4 by x 32 bx).
template <int EPI>
__global__ __launch_bounds__(512, 2) void k_g(
    const u16* __restrict__ A, const u16* __restrict__ Bt,
    u16* __restrict__ o0, u16* __restrict__ o1, u16* __restrict__ o2,
    const float* __restrict__ b0, const float* __restrict__ b1,
    const float* __restrict__ b2) {
  __shared__ u16 As[2 * 128 * 32];  // 16KB  [kh][128][32]
  __shared__ u16 Bs[2 * 256 * 32];  // 32KB  [kh][256][32]
  const int tid = threadIdx.x;
  const int w = tid >> 6, l = tid & 63;
  const int wm = w >> 2, wn = w & 3;  // 2M x 4N waves

  const int bid = (int)blockIdx.x;
  const int xcd = bid & 7, c = bid >> 3;
  int bx, by;
  if (EPI == 0) { by = c % 12; bx = xcd * 32 + c / 12; }
  else          { by = c & 3;  bx = xcd * 32 + (c >> 2); }

  const long row0 = (long)bx * 128;
  const long col0 = (long)by * 256;
  const u16* Bt2 = Bt + (EPI == 1 ? ((size_t)(row0 >> 12) << 20) : (size_t)0);

  f32x4 acc[4][4];
#pragma unroll
  for (int i = 0; i < 4; ++i)
#pragma unroll
    for (int j = 0; j < 4; ++j) acc[i][j] = (f32x4){0.f, 0.f, 0.f, 0.f};

  // staging: A = 1024 chunks of 16B (2/thread: kh0,kh1); B = 2048 (4/thread).
  // chunk -> row (tid>>2) [+128 for B's odd i], k-slot (tid&3)*8, kh offset 32.
  const u16* gA = A + (row0 + (tid >> 2)) * 1024 + (tid & 3) * 8;
  const u16* gB = Bt2 + (col0 + (tid >> 2)) * 1024 + (tid & 3) * 8;
  u16* lA = As + (w * 64) * 8;  // wave-uniform; lane offset l*16B implicit
  u16* lB = Bs + (w * 64) * 8;

  const int aoff = (wm * 64 + (l & 15)) * 32 + (l >> 4) * 8;
  const int boff = (wn * 64 + (l & 15)) * 32 + (l >> 4) * 8;

  for (int kt = 0; kt < 1024; kt += 64) {
    // A: kh=0, kh=1
    gload16(gA + kt, lA);
    gload16(gA + kt + 32, lA + 4096);
    // B: i = (kh<<1)|rowhalf; dest linear chunk i*512 + tid
#pragma unroll
    for (int i = 0; i < 4; ++i) {
      const int go = (i & 1) * 131072 + (i >> 1) * 32 + kt;
      gload16(gB + go, lB + i * 4096);
    }
    __syncthreads();  // drains vmcnt -> tiles visible
#pragma unroll
    for (int kh = 0; kh < 2; ++kh) {
      bf16x8 af[4], bfr[4];
#pragma unroll
      for (int mi = 0; mi < 4; ++mi)
        af[mi] = *(const bf16x8*)(As + kh * 4096 + aoff + mi * 512);
#pragma unroll
      for (int ni = 0; ni < 4; ++ni)
        bfr[ni] = *(const bf16x8*)(Bs + kh * 8192 + boff + ni * 512);
#pragma unroll
      for (int mi = 0; mi < 4; ++mi)
#pragma unroll
        for (int ni = 0; ni < 4; ++ni)
          acc[mi][ni] = __builtin_amdgcn_mfma_f32_16x16x32_bf16(
              af[mi], bfr[ni], acc[mi][ni], 0, 0, 0);
    }
    __syncthreads();  // all reads done before next stage overwrites
  }

  // Epilogue: D row = (l>>4)*4+reg, col = l&15 within each 16x16 frag
  const int rb = (int)row0 + wm * 64 + ((l >> 4) << 2);
  const int cb = (int)col0 + wn * 64 + (l & 15);
  if (EPI == 0) {
    const int seg = (int)(col0 >> 10);  // 0:Q 1:K 2:V (uniform per block)
    const int cl = cb & 1023;
    u16* outp = (seg == 0) ? o0 : (seg == 1) ? o1 : o2;
    const float* bias = (seg == 0) ? b0 : (seg == 1) ? b1 : b2;
#pragma unroll
    for (int mi = 0; mi < 4; ++mi)
#pragma unroll
      for (int ni = 0; ni < 4; ++ni) {
        const float bv_ = bias[cl + ni * 16];
#pragma unroll
        for (int r = 0; r < 4; ++r) {
          float v = acc[mi][ni][r] + bv_;
          if (seg < 2) v = v > 0.f ? v : expm1f(v);  // elu
          outp[(size_t)(rb + mi * 16 + r) * 1024 + cl + ni * 16] = f2bf(v);
        }
      }
  } else {
#pragma unroll
    for (int mi = 0; mi < 4; ++mi)
#pragma unroll
      for (int ni = 0; ni < 4; ++ni)
#pragma unroll
        for (int r = 0; r < 4; ++r)
          o0[(size_t)(rb + mi * 16 + r) * 1024 + cb + ni * 16] =
              f2bf(acc[mi][ni][r]);
  }
}

// ---------------------------------------------------------------------------
// Per-(token,head) L2 norm for Q only, in place (K norm fused into k_kv).
__global__ __launch_bounds__(256) void k_qn(u16* __restrict__ eq) {
  const int tid = threadIdx.x, w = tid >> 6, l = tid & 63;
  const long t = (long)blockIdx.x * 4 + w;
  const size_t base = (size_t)t * 1024 + (l >> 2) * 64 + (l & 3) * 16;
  u16x8 a = *(const u16x8*)(eq + base);
  u16x8 b = *(const u16x8*)(eq + base + 8);
  float f[16];
#pragma unroll
  for (int j = 0; j < 8; ++j) { f[j] = bf2f(a[j]); f[8 + j] = bf2f(b[j]); }
  float ss = 0.f;
#pragma unroll
  for (int j = 0; j < 16; ++j) ss += f[j] * f[j];
  ss += __shfl_xor(ss, 1);
  ss += __shfl_xor(ss, 2);
  const float rq = rsqrtf(ss);
  u16x8 oa, ob;
#pragma unroll
  for (int j = 0; j < 8; ++j) { oa[j] = f2bf(f[j] * rq); ob[j] = f2bf(f[8 + j] * rq); }
  *(u16x8*)(eq + base) = oa;
  *(u16x8*)(eq + base + 8) = ob;
}

// ---------------------------------------------------------------------------
// kv partials via MFMA with FUSED K-normalization:
// kvp[sc][b][h][d][e] = sum_{s in quarter} (ek[s,d]/||ek[s,:]||) * v[s,e]
__global__ __launch_bounds__(256) void k_kv(const u16* __restrict__ ek,
                                            const u16* __restrict__ vv,
                                            float* __restrict__ kvp) {
  __shared__ __align__(16) char lds[69632];  // 4 regions x 17408 B
  const int tid = threadIdx.x, w = tid >> 6, l = tid & 63;
  const int bid = blockIdx.x;  // sc + 4*(h + 16*b)
  const int sc = bid & 3, h = (bid >> 2) & 15, b = bid >> 6;
  const int tp = l >> 3, dgrp = l & 7;
  char* myk = lds + w * 17408;       // knT tile [64 d][64 s] u16 (128B rows)
  char* myv = myk + 8192;            // vT tile
  const long Tw = (long)b * 4096 + sc * 1024 + w * 256;
  const int d0 = dgrp * 8;

  f32x4 acc[4][4];
#pragma unroll
  for (int i = 0; i < 4; ++i)
#pragma unroll
    for (int j = 0; j < 4; ++j) acc[i][j] = (f32x4){0.f, 0.f, 0.f, 0.f};

  for (int st = 0; st < 4; ++st) {
    // ---- transpose-stage 64 tokens x 64 d for kn (normalized) and v
#pragma unroll
    for (int ro = 0; ro < 4; ++ro) {
      const int tl = ro * 16 + tp * 2;  // even local token
      const long T = Tw + st * 64 + tl;
      const u16* kp = ek + (size_t)T * 1024 + h * 64 + d0;
      const u16* vp = vv + (size_t)T * 1024 + h * 64 + d0;
      u16x8 k0 = *(const u16x8*)kp, k1 = *(const u16x8*)(kp + 1024);
      u16x8 v0 = *(const u16x8*)vp, v1 = *(const u16x8*)(vp + 1024);
      float f0[8], f1[8], s0 = 0.f, s1 = 0.f;
#pragma unroll
      for (int j = 0; j < 8; ++j) {
        f0[j] = bf2f(k0[j]); s0 += f0[j] * f0[j];
        f1[j] = bf2f(k1[j]); s1 += f1[j] * f1[j];
      }
      s0 += __shfl_xor(s0, 1); s0 += __shfl_xor(s0, 2); s0 += __shfl_xor(s0, 4);
      s1 += __shfl_xor(s1, 1); s1 += __shfl_xor(s1, 2); s1 += __shfl_xor(s1, 4);
      const float r0 = rsqrtf(s0), r1 = rsqrtf(s1);
#pragma unroll
      for (int j = 0; j < 8; ++j) {
        const int d = d0 + j;
        const int sw = (d & 8) ? 32 : 0;
        *(uint32_t*)(myk + d * 128 + ((tl * 2) ^ sw)) =
            (uint32_t)f2bf(f0[j] * r0) | ((uint32_t)f2bf(f1[j] * r1) << 16);
        *(uint32_t*)(myv + d * 128 + ((tl * 2) ^ sw)) =
            (uint32_t)v0[j] | ((uint32_t)v1[j] << 16);
      }
    }
    // ---- compute: D[d][e] += knT-tile . vT-tile  (K = 64 = 2 slices)
#pragma unroll
    for (int ksl = 0; ksl < 2; ++ksl) {
      const int sb = (ksl * 64 + (l >> 4) * 16) ^ ((l & 8) ? 32 : 0);
      bf16x8 a[4], bb[4];
#pragma unroll
      for (int mf = 0; mf < 4; ++mf)
        a[mf] = *(const bf16x8*)(myk + (mf * 16 + (l & 15)) * 128 + sb);
#pragma unroll
      for (int nf = 0; nf < 4; ++nf)
        bb[nf] = *(const bf16x8*)(myv + (nf * 16 + (l & 15)) * 128 + sb);
#pragma unroll
      for (int mf = 0; mf < 4; ++mf)
#pragma unroll
        for (int nf = 0; nf < 4; ++nf)
          acc[mf][nf] = __builtin_amdgcn_mfma_f32_16x16x32_bf16(
              a[mf], bb[nf], acc[mf][nf], 0, 0, 0);
    }
  }

  // ---- block reduction of 4 wave partials (rows padded to 68 f32)
  __syncthreads();
  float* lf = (float*)(lds + w * 17408);
#pragma unroll
  for (int mf = 0; mf < 4; ++mf)
#pragma unroll
    for (int nf = 0; nf < 4; ++nf)
#pragma unroll
      for (int r = 0; r < 4; ++r)
        lf[(mf * 16 + (l >> 4) * 4 + r) * 68 + nf * 16 + (l & 15)] =
            acc[mf][nf][r];
  __syncthreads();
  float* op = kvp + ((size_t)(sc * 8 + b) * 16 + h) * 4096;
  const float* l0 = (const float*)lds;
  const int dd = tid >> 2, eb = (tid & 3) * 16;
#pragma unroll
  for (int c = 0; c < 4; ++c) {
    f32x4 s = *(const f32x4*)(l0 + dd * 68 + eb + c * 4);
#pragma unroll
    for (int w2 = 1; w2 < 4; ++w2)
      s += *(const f32x4*)(l0 + w2 * 4352 + dd * 68 + eb + c * 4);
    *(f32x4*)(op + tid * 16 + c * 4) = s;
  }
}

// ---------------------------------------------------------------------------
// M2t[b][n][h*64+d] = (1/8) * sum_e kv[b,h][d][e] * Wdt[n][h*64+e] via MFMA,
// with FUSED kv partial-sum (reads the 4 kvp partials, sums in reg, stages
// bf16 tile to LDS).
__global__ __launch_bounds__(256) void k_m2(const float* __restrict__ kvp,
                                            const u16* __restrict__ Wdt,
                                            u16* __restrict__ M2t) {
  __shared__ __align__(16) u16 lds[12288];  // kv: [64][64] @0; WdT: [128][64] @4096
  const int tid = threadIdx.x;
  const int w = tid >> 6, l = tid & 63;
  const int n0 = (int)blockIdx.x * 128, h = (int)blockIdx.y,
            b = (int)blockIdx.z;

  // stage WdT tile (16KB = 1024 x 16B): row n0+(c>>3), e-slot c&7 (+h*64)
#pragma unroll
  for (int g = 0; g < 4; ++g) {
    const int c = g * 256 + tid;
    gload16(Wdt + (size_t)(n0 + (c >> 3)) * 1024 + h * 64 + (c & 7) * 8,
            lds + 4096 + (g * 256 + w * 64) * 8);
  }
  // stage kv tile with fused 4-partial sum (reg-staged, linear ds_write)
  const size_t kvbase = ((size_t)(b * 16 + h)) * 4096;
#pragma unroll
  for (int g = 0; g < 2; ++g) {
    const int c = g * 256 + tid;  // chunk: row c>>3, e-slot c&7
    const float* p = kvp + kvbase + (size_t)(c >> 3) * 64 + (c & 7) * 8;
    f32x4 s0 = *(const f32x4*)p;
    f32x4 s1 = *(const f32x4*)(p + 4);
#pragma unroll
    for (int sc = 1; sc < 4; ++sc) {
      s0 += *(const f32x4*)(p + (size_t)sc * 524288);
      s1 += *(const f32x4*)(p + (size_t)sc * 524288 + 4);
    }
    u16x8 o;
#pragma unroll
    for (int j = 0; j < 4; ++j) { o[j] = f2bf(s0[j]); o[4 + j] = f2bf(s1[j]); }
    *(u16x8*)(lds + c * 8) = o;
  }
  __syncthreads();

  f32x4 acc[4][2];
#pragma unroll
  for (int i = 0; i < 4; ++i)
#pragma unroll
    for (int j = 0; j < 2; ++j) acc[i][j] = (f32x4){0.f, 0.f, 0.f, 0.f};

#pragma unroll
  for (int kh = 0; kh < 2; ++kh) {
    bf16x8 a[4], bb[2];
#pragma unroll
    for (int mf = 0; mf < 4; ++mf)
      a[mf] = *(const bf16x8*)(lds + (mf * 16 + (l & 15)) * 64 + kh * 32 +
                               (l >> 4) * 8);
#pragma unroll
    for (int nf = 0; nf < 2; ++nf)
      bb[nf] = *(const bf16x8*)(lds + 4096 +
                                (w * 32 + nf * 16 + (l & 15)) * 64 + kh * 32 +
                                (l >> 4) * 8);
#pragma unroll
    for (int mf = 0; mf < 4; ++mf)
#pragma unroll
      for (int nf = 0; nf < 2; ++nf)
        acc[mf][nf] = __builtin_amdgcn_mfma_f32_16x16x32_bf16(
            a[mf], bb[nf], acc[mf][nf], 0, 0, 0);
  }

  // store: D[d][n]; col n = w*32+nf*16+(l&15); rows d = mf*16+(l>>4)*4+r
  u16* outb = M2t + ((size_t)b << 20) + h * 64;
#pragma unroll
  for (int mf = 0; mf < 4; ++mf)
#pragma unroll
    for (int nf = 0; nf < 2; ++nf) {
      const int col = w * 32 + nf * 16 + (l & 15);
      u16x4 o;
#pragma unroll
      for (int r = 0; r < 4; ++r) o[r] = f2bf(acc[mf][nf][r] * 0.125f);
      *(u16x4*)(outb + (size_t)(n0 + col) * 1024 + mf * 16 + (l >> 4) * 4) = o;
    }
}

// ---------------------------------------------------------------------------
// LayerNorm(hid + bd + xb) * gamma + beta  -> fp32 out
__global__ __launch_bounds__(256) void k_ln(const u16* __restrict__ hid,
                                            const u16* __restrict__ xb,
                                            const float* __restrict__ bd,
                                            const float* __restrict__ g,
                                            const float* __restrict__ be,
                                            float* __restrict__ out) {
  const int tid = threadIdx.x, w = tid >> 6, l = tid & 63;
  const size_t base = (size_t)blockIdx.x * 1024 + tid * 4;
  u16x4 h4 = *(const u16x4*)(hid + base);
  u16x4 x4 = *(const u16x4*)(xb + base);
  f32x4 bd4 = *(const f32x4*)(bd + tid * 4);
  float v[4];
#pragma unroll
  for (int j = 0; j < 4; ++j) v[j] = bf2f(h4[j]) + bf2f(x4[j]) + bd4[j];
  float s = v[0] + v[1] + v[2] + v[3];
  float ss = v[0] * v[0] + v[1] * v[1] + v[2] * v[2] + v[3] * v[3];
#pragma unroll
  for (int o = 32; o > 0; o >>= 1) {
    s += __shfl_xor(s, o);
    ss += __shfl_xor(ss, o);
  }
  __shared__ float red[8];
  if (l == 0) { red[w] = s; red[w + 4] = ss; }
  __syncthreads();
  s = red[0] + red[1] + red[2] + red[3];
  ss = red[4] + red[5] + red[6] + red[7];
  const float mu = s * (1.0f / 1024.0f);
  const float var = ss * (1.0f / 1024.0f) - mu * mu;
  const float rstd = rsqrtf(var + 1e-12f);
  f32x4 g4 = *(const f32x4*)(g + tid * 4);
  f32x4 b4 = *(const f32x4*)(be + tid * 4);
  f32x4 o;
#pragma unroll
  for (int j = 0; j < 4; ++j) o[j] = (v[j] - mu) * rstd * g4[j] + b4[j];
  *(f32x4*)(out + base) = o;
}

// ---------------------------------------------------------------------------
extern "C" void kernel_launch(void* const* d_in, const int* in_sizes, int n_in,
                              void* d_out, int out_size, void* d_ws,
                              size_t ws_size, hipStream_t stream) {
  const float* X = (const float*)d_in[0];
  const float* Wq = (const float*)d_in[1];
  const float* bq = (const float*)d_in[2];
  const float* Wk = (const float*)d_in[3];
  const float* bk = (const float*)d_in[4];
  const float* Wv = (const float*)d_in[5];
  const float* bv = (const float*)d_in[6];
  const float* Wd = (const float*)d_in[7];
  const float* bd = (const float*)d_in[8];
  const float* gamma = (const float*)d_in[9];
  const float* beta = (const float*)d_in[10];
  float* out = (float*)d_out;

  char* ws = (char*)d_ws;
  u16* Xb = (u16*)(ws);                       // 64 MiB
  u16* Wt = (u16*)(ws + 67108864);            // 6 MiB  [3072][1024] bf16
  u16* eq = (u16*)(ws + 73400320);            // 64 MiB (-> qn in place)
  u16* ek = (u16*)(ws + 140509184);           // 64 MiB (raw eluK; later hid)
  u16* vb = (u16*)(ws + 207618048);           // 64 MiB
  u16* Wdt = (u16*)(ws + 274726912);          // 2 MiB  [1024][1024] bf16
  float* kvp = (float*)(ws + 276824064);      // 8 MiB (4 partials)
  u16* M2t = (u16*)(ws + 285212672);          // 16 MiB  [8][1024][1024] bf16
  // total ws use: 301,989,888 bytes

  k_cvt_x<<<16384, 256, 0, stream>>>(X, Xb);
  k_wt<<<dim3(4, 128, 4), 256, 0, stream>>>(Wq, Wk, Wv, Wd, Wt, Wdt);
  k_g<0><<<3072, 512, 0, stream>>>(Xb, Wt, eq, ek, vb, bq, bk, bv);
  k_qn<<<8192, 256, 0, stream>>>(eq);
  k_kv<<<512, 256, 0, stream>>>(ek, vb, kvp);
  k_m2<<<dim3(8, 16, 8), 256, 0, stream>>>(kvp, Wdt, M2t);
  k_g<1><<<1024, 512, 0, stream>>>(eq, M2t, ek, nullptr, nullptr, nullptr,
                                   nullptr, nullptr);
  k_ln<<<32768, 256, 0, stream>>>(ek, Xb, bd, gamma, beta, out);
}